// Round 10
// baseline (324.973 us; speedup 1.0000x reference)
//
#include <hip/hip_runtime.h>
#include <hip/hip_bf16.h>

#define N_NODES 10000
#define N_EDGES 320000
#define F_IN    3000
#define KP      3008   // F_IN padded to multiple of 32
#define H1      512
#define H2      64
#define CAP     128    // max in-degree bucket capacity (Poisson mean 32)
#define NT      (KP / 32)   // 94 K-tiles in gemm1

typedef float  f32x4  __attribute__((ext_vector_type(4)));
typedef short  bf16x8 __attribute__((ext_vector_type(8)));
typedef unsigned short us8 __attribute__((ext_vector_type(8)));

// fp32 -> bf16 bits, round-to-nearest-even
__device__ __forceinline__ unsigned short f2b(float f) {
    union { float f; unsigned u; } v; v.f = f;
    unsigned r = v.u + 0x7FFF + ((v.u >> 16) & 1);
    return (unsigned short)(r >> 16);
}
__device__ __forceinline__ float b2f(unsigned short b) {
    union { unsigned u; float f; } v; v.u = ((unsigned)b) << 16;
    return v.f;
}

// async global->LDS, 16 B per lane; LDS base is WAVE-UNIFORM (HW adds lane*16)
#define GLOAD_LDS16(gptr, lptr)                                                             \
    __builtin_amdgcn_global_load_lds((const __attribute__((address_space(1))) void*)(gptr), \
                                     (__attribute__((address_space(3))) void*)(lptr),       \
                                     16, 0, 0)

// ---------------------------------------------------------------------------
// Merged prep: [0,1250) bucket | [1250,15938) convert_x | [15938,16314) convert_w1
// ---------------------------------------------------------------------------
#define NB_BUCKET 1250
#define NB_CONVX  14688   // ceil(10000*376/256)
#define NB_CONVW  376     // 47 k-tiles x 8 col-tiles

__global__ __launch_bounds__(256) void prep(const int* __restrict__ src,
                                            const int* __restrict__ dst,
                                            const float* __restrict__ w,
                                            const float* __restrict__ x,
                                            const float* __restrict__ W1,
                                            int* __restrict__ cnt,
                                            int* __restrict__ bsrc,
                                            float* __restrict__ bw,
                                            unsigned short* __restrict__ xb,
                                            unsigned short* __restrict__ w1t) {
    __shared__ float tr[64][65];
    const int b = blockIdx.x;
    const int t = threadIdx.x;
    if (b < NB_BUCKET) {
        int e = b * 256 + t;
        if (e >= N_EDGES) return;
        int d = dst[e];
        int slot = atomicAdd(&cnt[d], 1);
        if (slot < CAP) {
            bsrc[d * CAP + slot] = src[e];
            bw[d * CAP + slot]   = w[e];
        }
    } else if (b < NB_BUCKET + NB_CONVX) {
        int idx = (b - NB_BUCKET) * 256 + t;   // one thread per 8 bf16 outputs
        int r = idx / (KP / 8);
        int g = idx % (KP / 8);
        if (r >= N_NODES) return;
        us8 v;
        if (g * 8 + 8 <= F_IN) {
            float4 a = *(const float4*)&x[(size_t)r * F_IN + g * 8];
            float4 c = *(const float4*)&x[(size_t)r * F_IN + g * 8 + 4];
            v[0] = f2b(a.x); v[1] = f2b(a.y); v[2] = f2b(a.z); v[3] = f2b(a.w);
            v[4] = f2b(c.x); v[5] = f2b(c.y); v[6] = f2b(c.z); v[7] = f2b(c.w);
        } else {
            #pragma unroll
            for (int j = 0; j < 8; ++j) {
                int k = g * 8 + j;
                v[j] = (k < F_IN) ? f2b(x[(size_t)r * F_IN + k]) : (unsigned short)0;
            }
        }
        *(us8*)&xb[(size_t)r * KP + g * 8] = v;
    } else {
        // W1 [3000][512] fp32 -> w1t [512][3008] bf16, LDS-transposed tiles
        int bb = b - NB_BUCKET - NB_CONVX;
        int kBase = (bb >> 3) * 64;
        int cBase = (bb & 7) * 64;
        int col = cBase + (t & 63);
        #pragma unroll
        for (int i = 0; i < 16; ++i) {
            int row = kBase + i * 4 + (t >> 6);
            float v = (row < F_IN) ? W1[(size_t)row * H1 + col] : 0.f;
            tr[t & 63][i * 4 + (t >> 6)] = v;
        }
        __syncthreads();
        int c = t >> 2, kq = (t & 3) * 16;
        us8 o0, o1;
        #pragma unroll
        for (int j = 0; j < 8; ++j) { o0[j] = f2b(tr[c][kq + j]); o1[j] = f2b(tr[c][kq + 8 + j]); }
        *(us8*)&w1t[(size_t)(cBase + c) * KP + kBase + kq]     = o0;
        *(us8*)&w1t[(size_t)(cBase + c) * KP + kBase + kq + 8] = o1;
    }
}

// ---------------------------------------------------------------------------
// GEMM1: support1b(bf16) = x @ W1.  A = xb [10000][KP], B = w1t [512][KP].
// R10: 3-buffer, 2-tile-ahead pipeline (T4 deepened). Steady state keeps 2
// stages (6 gload_lds) in flight across barriers: vmcnt(6) only requires the
// 2-phases-old stage to have landed -> ~600-800 cyc latency budget (covers
// L3/HBM misses), vs R9's 1-ahead ~300 cyc. LDS 36 KB -> 4 blocks/CU.
// ---------------------------------------------------------------------------
__global__ __launch_bounds__(256, 4) void gemm1_mfma(const unsigned short* __restrict__ xb,
                                                     const unsigned short* __restrict__ w1t,
                                                     unsigned short* __restrict__ Cb) {
    __shared__ unsigned short As[3][128 * 32];   // 3 x 8 KB
    __shared__ unsigned short Bs[3][64 * 32];    // 3 x 4 KB
    // XCD swizzle: 640 = 8 xcd x 80; xcd owns 10 row-panels x 8 col-panels.
    const int f  = blockIdx.x;
    const int k8 = f & 7;
    const int jj = f >> 3;
    const int bx = k8 * 10 + (jj >> 3);   // bx=79 is padding (stores skipped)
    const int by = jj & 7;
    const int mBase = bx * 128;
    const int nBase = by * 64;

    const int t = threadIdx.x;
    const int wid = t >> 6, lane = t & 63;
    const int wr = (wid >> 1) * 64;    // wave row offset
    const int wc = (wid & 1) * 32;     // wave col offset
    const int fr = lane & 15;
    // read swizzle: global k-chunk g=(lane>>4) lives at LDS chunk g^(row&3)
    const int swz = (((lane >> 4) ^ (fr & 3)) << 3);   // element offset in row

    // staging: lane covers row (lane>>2) of its 16-row chunk, source chunk
    // pre-swizzled so linear LDS dest ends up swizzle-consistent (rule 21)
    const int srow   = lane >> 2;
    const int schunk = ((lane & 3) ^ (srow & 3)) * 8;  // bf16 elem offset
    const int arow0  = min(mBase + wid * 16 + srow, N_NODES - 1);
    const int arow1  = min(mBase + (wid + 4) * 16 + srow, N_NODES - 1);
    const int brow   = nBase + wid * 16 + srow;

    f32x4 acc[4][2] = {};

#define STAGE1(buf, k0)                                                                \
    do {                                                                               \
        unsigned short* ab = &As[buf][0];                                              \
        unsigned short* bb = &Bs[buf][0];                                              \
        GLOAD_LDS16(&xb[(size_t)arow0 * KP + (k0) + schunk], ab + wid * 512);          \
        GLOAD_LDS16(&xb[(size_t)arow1 * KP + (k0) + schunk], ab + (wid + 4) * 512);    \
        GLOAD_LDS16(&w1t[(size_t)brow * KP + (k0) + schunk], bb + wid * 512);          \
    } while (0)

#define COMPUTE1(buf)                                                          \
    do {                                                                       \
        const unsigned short* ar = &As[buf][0];                                \
        const unsigned short* br = &Bs[buf][0];                                \
        bf16x8 af[4], bfv[2];                                                  \
        _Pragma("unroll")                                                      \
        for (int m = 0; m < 4; ++m)                                            \
            af[m] = *(const bf16x8*)&ar[(wr + m * 16 + fr) * 32 + swz];        \
        _Pragma("unroll")                                                      \
        for (int n = 0; n < 2; ++n)                                            \
            bfv[n] = *(const bf16x8*)&br[(wc + n * 16 + fr) * 32 + swz];       \
        _Pragma("unroll")                                                      \
        for (int m = 0; m < 4; ++m)                                            \
            _Pragma("unroll")                                                  \
            for (int n = 0; n < 2; ++n)                                        \
                acc[m][n] = __builtin_amdgcn_mfma_f32_16x16x32_bf16(af[m], bfv[n], acc[m][n], 0, 0, 0); \
    } while (0)

    STAGE1(0, 0);
    STAGE1(1, 32);                    // 2 stages (6 loads) in flight
    int cs = 0;                       // compute buffer
    int ss = 2;                       // stage buffer = (tt+2)%3
    for (int tt = 0; tt < NT - 2; ++tt) {
        STAGE1(ss, (tt + 2) * 32);                   // +3 loads (2-ahead)
        asm volatile("s_waitcnt vmcnt(6)" ::: "memory");  // tile tt landed
        __builtin_amdgcn_s_barrier();                // visible to all waves
        __builtin_amdgcn_sched_barrier(0);
        COMPUTE1(cs);
        asm volatile("s_waitcnt lgkmcnt(0)" ::: "memory"); // ds_reads done
        __builtin_amdgcn_sched_barrier(0);
        __builtin_amdgcn_s_barrier();                // cs reusable next iter
        cs = (cs == 2) ? 0 : cs + 1;
        ss = (ss == 2) ? 0 : ss + 1;
    }
    // tile NT-2: only tile NT-1's 3 loads may remain outstanding
    asm volatile("s_waitcnt vmcnt(3)" ::: "memory");
    __builtin_amdgcn_s_barrier();
    __builtin_amdgcn_sched_barrier(0);
    COMPUTE1(cs);
    cs = (cs == 2) ? 0 : cs + 1;
    // tile NT-1: drain everything (no overwrite hazards remain)
    asm volatile("s_waitcnt vmcnt(0)" ::: "memory");
    __builtin_amdgcn_s_barrier();
    COMPUTE1(cs);

#undef STAGE1
#undef COMPUTE1

    // C/D layout: col = lane&15, row = (lane>>4)*4 + reg
    #pragma unroll
    for (int m = 0; m < 4; ++m) {
        int rbase = mBase + wr + m * 16 + (lane >> 4) * 4;
        #pragma unroll
        for (int n = 0; n < 2; ++n) {
            int col = nBase + wc + n * 16 + (lane & 15);
            #pragma unroll
            for (int i = 0; i < 4; ++i) {
                int row = rbase + i;
                if (row < N_NODES)
                    Cb[(size_t)row * H1 + col] = f2b(acc[m][n][i]);
            }
        }
    }
}

// ---------------------------------------------------------------------------
// FUSED gather h1 (+ReLU) + GEMM2/3: block owns 16 nodes. 8 waves gather
// their 2 nodes each into LDS, then transform 512->128 (W2|W3) from LDS.
// Output sup2 stored bf16 (halves gather_muvar's L3 read).
// ---------------------------------------------------------------------------
__global__ __launch_bounds__(512) void gather_gemm23(const unsigned short* __restrict__ sup,
                                                     const int* __restrict__ cnt,
                                                     const int* __restrict__ bsrc,
                                                     const float* __restrict__ bw,
                                                     const float* __restrict__ W2,
                                                     const float* __restrict__ W3,
                                                     unsigned short* __restrict__ sup2b) {
    __shared__ float hs[16][H1];   // 32 KB
    const int t = threadIdx.x;
    const int wid = t >> 6, lane = t & 63;
    const int rBase = blockIdx.x * 16;

    #pragma unroll
    for (int i = 0; i < 2; ++i) {
        const int local = wid * 2 + i;
        const int n = rBase + local;
        const int deg = min(cnt[n], CAP);
        float acc[8] = {};
        for (int e = 0; e < deg; ++e) {
            int   s = bsrc[n * CAP + e];
            float w = bw[n * CAP + e];
            us8 v = *(const us8*)&sup[(size_t)s * H1 + lane * 8];
            #pragma unroll
            for (int j = 0; j < 8; ++j) acc[j] += w * b2f(v[j]);
        }
        *(float4*)&hs[local][lane * 8] =
            make_float4(fmaxf(acc[0], 0.f), fmaxf(acc[1], 0.f), fmaxf(acc[2], 0.f), fmaxf(acc[3], 0.f));
        *(float4*)&hs[local][lane * 8 + 4] =
            make_float4(fmaxf(acc[4], 0.f), fmaxf(acc[5], 0.f), fmaxf(acc[6], 0.f), fmaxf(acc[7], 0.f));
    }
    __syncthreads();

    const int col = t & 127;
    const int rg  = (t >> 7) * 4;
    const float* W = (col < 64) ? (W2 + col) : (W3 + (col - 64));
    float acc2[4] = {};
    for (int k = 0; k < H1; ++k) {
        float wv = W[k * 64];
        #pragma unroll
        for (int i = 0; i < 4; ++i) acc2[i] += wv * hs[rg + i][k];
    }
    #pragma unroll
    for (int i = 0; i < 4; ++i)
        sup2b[(size_t)(rBase + rg + i) * 128 + col] = f2b(acc2[i]);
}

// ---------------------------------------------------------------------------
// Gather mu/logvar from bf16 sup2: 16 nodes/block, 16 lanes x us8 per node.
// ---------------------------------------------------------------------------
__global__ __launch_bounds__(256) void gather_muvar(const unsigned short* __restrict__ sup2b,
                                                    const int* __restrict__ cnt,
                                                    const int* __restrict__ bsrc,
                                                    const float* __restrict__ bw,
                                                    float* __restrict__ mu,
                                                    float* __restrict__ lv,
                                                    unsigned short* __restrict__ mub) {
    const int n  = blockIdx.x * 16 + (threadIdx.x >> 4);
    const int c8 = (threadIdx.x & 15) * 8;
    const int deg = min(cnt[n], CAP);
    float acc[8] = {};
    for (int e = 0; e < deg; ++e) {
        int   s = bsrc[n * CAP + e];
        float w = bw[n * CAP + e];
        us8 v = *(const us8*)&sup2b[(size_t)s * 128 + c8];
        #pragma unroll
        for (int j = 0; j < 8; ++j) acc[j] += w * b2f(v[j]);
    }
    if (c8 < 64) {
        *(float4*)&mu[(size_t)n * 64 + c8]     = make_float4(acc[0], acc[1], acc[2], acc[3]);
        *(float4*)&mu[(size_t)n * 64 + c8 + 4] = make_float4(acc[4], acc[5], acc[6], acc[7]);
        us8 o;
        #pragma unroll
        for (int j = 0; j < 8; ++j) o[j] = f2b(acc[j]);
        *(us8*)&mub[(size_t)n * 64 + c8] = o;
    } else {
        *(float4*)&lv[(size_t)n * 64 + (c8 - 64)]     = make_float4(acc[0], acc[1], acc[2], acc[3]);
        *(float4*)&lv[(size_t)n * 64 + (c8 - 64) + 4] = make_float4(acc[4], acc[5], acc[6], acc[7]);
    }
}

// ---------------------------------------------------------------------------
// pred = mu @ mu.T via bf16 MFMA; mub (1.28 MB) is L2-resident.
// LDS-staged coalesced rows + nontemporal stores (400 MB write-once stream).
// ---------------------------------------------------------------------------
__global__ __launch_bounds__(256) void pred_mfma(const unsigned short* __restrict__ mub,
                                                 float* __restrict__ pred) {
    __shared__ float st[4][16][68];
    const int t = threadIdx.x, wid = t >> 6, lane = t & 63;
    const int rb = blockIdx.x * 128 + (wid >> 1) * 64;
    const int cb = blockIdx.y * 128 + (wid & 1) * 64;
    const int fr = lane & 15, fk = (lane >> 4) * 8;
    f32x4 acc[4][4] = {};

    #pragma unroll
    for (int ks = 0; ks < 2; ++ks) {
        bf16x8 af[4], bfv[4];
        #pragma unroll
        for (int m = 0; m < 4; ++m) {
            int r = min(rb + m * 16 + fr, N_NODES - 1);
            af[m] = *(const bf16x8*)&mub[(size_t)r * 64 + ks * 32 + fk];
        }
        #pragma unroll
        for (int n = 0; n < 4; ++n) {
            int c = min(cb + n * 16 + fr, N_NODES - 1);
            bfv[n] = *(const bf16x8*)&mub[(size_t)c * 64 + ks * 32 + fk];
        }
        #pragma unroll
        for (int m = 0; m < 4; ++m)
            #pragma unroll
            for (int n = 0; n < 4; ++n)
                acc[m][n] = __builtin_amdgcn_mfma_f32_16x16x32_bf16(af[m], bfv[n], acc[m][n], 0, 0, 0);
    }

    #pragma unroll
    for (int m = 0; m < 4; ++m) {
        #pragma unroll
        for (int n = 0; n < 4; ++n)
            #pragma unroll
            for (int i = 0; i < 4; ++i)
                st[wid][(lane >> 4) * 4 + i][n * 16 + (lane & 15)] = acc[m][n][i];
        // wave-private region: in-wave lgkmcnt ordering suffices (no barrier)
        int rbase = rb + m * 16;
        #pragma unroll
        for (int it = 0; it < 4; ++it) {
            int row   = it * 4 + (lane >> 4);
            int chunk = lane & 15;
            int grow  = rbase + row;
            int gcol  = cb + chunk * 4;
            if (grow < N_NODES) {
                f32x4 v = *(const f32x4*)&st[wid][row][chunk * 4];
                if (gcol + 3 < N_NODES) {
                    __builtin_nontemporal_store(v, (f32x4*)&pred[(size_t)grow * N_NODES + gcol]);
                } else {
                    #pragma unroll
                    for (int j = 0; j < 4; ++j)
                        if (gcol + j < N_NODES)
                            __builtin_nontemporal_store(v[j], &pred[(size_t)grow * N_NODES + gcol + j]);
                }
            }
        }
    }
}

// ---------------------------------------------------------------------------
extern "C" void kernel_launch(void* const* d_in, const int* in_sizes, int n_in,
                              void* d_out, int out_size, void* d_ws, size_t ws_size,
                              hipStream_t stream) {
    const float* x    = (const float*)d_in[0];
    const int*   esrc = (const int*)d_in[1];
    const int*   edst = (const int*)d_in[2];
    const float* ew   = (const float*)d_in[3];
    const float* W1   = (const float*)d_in[4];
    const float* W2   = (const float*)d_in[5];
    const float* W3   = (const float*)d_in[6];

    float* pred = (float*)d_out;
    float* mu   = pred + (size_t)N_NODES * N_NODES;
    float* lv   = mu   + (size_t)N_NODES * H2;

    char* ws = (char*)d_ws;
    unsigned short* sup1b = (unsigned short*)ws; ws += (size_t)N_NODES * H1 * sizeof(short);
    unsigned short* sup2b = (unsigned short*)ws; ws += (size_t)N_NODES * 2 * H2 * sizeof(short);
    int*   cnt      = (int*)ws;   ws += (size_t)N_NODES * sizeof(int);
    int*   bsrc     = (int*)ws;   ws += (size_t)N_NODES * CAP * sizeof(int);
    float* bw       = (float*)ws; ws += (size_t)N_NODES * CAP * sizeof(float);
    unsigned short* xb  = (unsigned short*)ws; ws += (size_t)N_NODES * KP * sizeof(short);
    unsigned short* w1t = (unsigned short*)ws; ws += (size_t)H1 * KP * sizeof(short);
    unsigned short* mub = (unsigned short*)ws; ws += (size_t)N_NODES * H2 * sizeof(short);

    (void)hipMemsetAsync(cnt, 0, N_NODES * sizeof(int), stream);
    prep<<<NB_BUCKET + NB_CONVX + NB_CONVW, 256, 0, stream>>>(esrc, edst, ew, x, W1,
                                                              cnt, bsrc, bw, xb, w1t);
    gemm1_mfma<<<640, 256, 0, stream>>>(xb, w1t, sup1b);
    gather_gemm23<<<N_NODES / 16, 512, 0, stream>>>(sup1b, cnt, bsrc, bw, W2, W3, sup2b);
    gather_muvar<<<N_NODES / 16, 256, 0, stream>>>(sup2b, cnt, bsrc, bw, mu, lv, mub);
    pred_mfma<<<dim3((N_NODES + 127) / 128, (N_NODES + 127) / 128), 256, 0, stream>>>(mub, pred);
}

// Round 11
// 299.735 us; speedup vs baseline: 1.0842x; 1.0842x over previous
//
#include <hip/hip_runtime.h>
#include <hip/hip_bf16.h>

#define N_NODES 10000
#define N_EDGES 320000
#define F_IN    3000
#define KP      3008   // F_IN padded to multiple of 32
#define H1      512
#define H2      64
#define CAP     128    // max in-degree bucket capacity (Poisson mean 32)
#define NT      (KP / 32)   // 94 K-tiles in gemm1

typedef float  f32x4  __attribute__((ext_vector_type(4)));
typedef short  bf16x8 __attribute__((ext_vector_type(8)));
typedef unsigned short us8 __attribute__((ext_vector_type(8)));

// fp32 -> bf16 bits, round-to-nearest-even
__device__ __forceinline__ unsigned short f2b(float f) {
    union { float f; unsigned u; } v; v.f = f;
    unsigned r = v.u + 0x7FFF + ((v.u >> 16) & 1);
    return (unsigned short)(r >> 16);
}
__device__ __forceinline__ float b2f(unsigned short b) {
    union { unsigned u; float f; } v; v.u = ((unsigned)b) << 16;
    return v.f;
}

// async global->LDS, 16 B per lane; LDS base is WAVE-UNIFORM (HW adds lane*16)
#define GLOAD_LDS16(gptr, lptr)                                                             \
    __builtin_amdgcn_global_load_lds((const __attribute__((address_space(1))) void*)(gptr), \
                                     (__attribute__((address_space(3))) void*)(lptr),       \
                                     16, 0, 0)

// ---------------------------------------------------------------------------
// Merged prep: [0,1250) bucket | [1250,15938) convert_x | [15938,16314) convert_w1
// ---------------------------------------------------------------------------
#define NB_BUCKET 1250
#define NB_CONVX  14688   // ceil(10000*376/256)
#define NB_CONVW  376     // 47 k-tiles x 8 col-tiles

__global__ __launch_bounds__(256) void prep(const int* __restrict__ src,
                                            const int* __restrict__ dst,
                                            const float* __restrict__ w,
                                            const float* __restrict__ x,
                                            const float* __restrict__ W1,
                                            int* __restrict__ cnt,
                                            int* __restrict__ bsrc,
                                            float* __restrict__ bw,
                                            unsigned short* __restrict__ xb,
                                            unsigned short* __restrict__ w1t) {
    __shared__ float tr[64][65];
    const int b = blockIdx.x;
    const int t = threadIdx.x;
    if (b < NB_BUCKET) {
        int e = b * 256 + t;
        if (e >= N_EDGES) return;
        int d = dst[e];
        int slot = atomicAdd(&cnt[d], 1);
        if (slot < CAP) {
            bsrc[d * CAP + slot] = src[e];
            bw[d * CAP + slot]   = w[e];
        }
    } else if (b < NB_BUCKET + NB_CONVX) {
        int idx = (b - NB_BUCKET) * 256 + t;   // one thread per 8 bf16 outputs
        int r = idx / (KP / 8);
        int g = idx % (KP / 8);
        if (r >= N_NODES) return;
        us8 v;
        if (g * 8 + 8 <= F_IN) {
            float4 a = *(const float4*)&x[(size_t)r * F_IN + g * 8];
            float4 c = *(const float4*)&x[(size_t)r * F_IN + g * 8 + 4];
            v[0] = f2b(a.x); v[1] = f2b(a.y); v[2] = f2b(a.z); v[3] = f2b(a.w);
            v[4] = f2b(c.x); v[5] = f2b(c.y); v[6] = f2b(c.z); v[7] = f2b(c.w);
        } else {
            #pragma unroll
            for (int j = 0; j < 8; ++j) {
                int k = g * 8 + j;
                v[j] = (k < F_IN) ? f2b(x[(size_t)r * F_IN + k]) : (unsigned short)0;
            }
        }
        *(us8*)&xb[(size_t)r * KP + g * 8] = v;
    } else {
        // W1 [3000][512] fp32 -> w1t [512][3008] bf16, LDS-transposed tiles
        int bb = b - NB_BUCKET - NB_CONVX;
        int kBase = (bb >> 3) * 64;
        int cBase = (bb & 7) * 64;
        int col = cBase + (t & 63);
        #pragma unroll
        for (int i = 0; i < 16; ++i) {
            int row = kBase + i * 4 + (t >> 6);
            float v = (row < F_IN) ? W1[(size_t)row * H1 + col] : 0.f;
            tr[t & 63][i * 4 + (t >> 6)] = v;
        }
        __syncthreads();
        int c = t >> 2, kq = (t & 3) * 16;
        us8 o0, o1;
        #pragma unroll
        for (int j = 0; j < 8; ++j) { o0[j] = f2b(tr[c][kq + j]); o1[j] = f2b(tr[c][kq + 8 + j]); }
        *(us8*)&w1t[(size_t)(cBase + c) * KP + kBase + kq]     = o0;
        *(us8*)&w1t[(size_t)(cBase + c) * KP + kBase + kq + 8] = o1;
    }
}

// ---------------------------------------------------------------------------
// GEMM1: support1b(bf16) = x @ W1.  A = xb [10000][KP], B = w1t [512][KP].
// R9-proven form: 2-buffer counted-vmcnt pipeline (vmcnt(3) keeps next-tile
// loads in flight across the barrier), swizzle-consistent gload_lds staging,
// XCD-swizzled grid, 6 blocks/CU. (R10's 2-ahead depth was neutral -> gemm1
// is not stage-latency-bound; schedule frozen here.)
// ---------------------------------------------------------------------------
__global__ __launch_bounds__(256, 6) void gemm1_mfma(const unsigned short* __restrict__ xb,
                                                     const unsigned short* __restrict__ w1t,
                                                     unsigned short* __restrict__ Cb) {
    __shared__ unsigned short As[2][128 * 32];   // 2 x 8 KB
    __shared__ unsigned short Bs[2][64 * 32];    // 2 x 4 KB
    const int f  = blockIdx.x;
    const int k8 = f & 7;
    const int jj = f >> 3;
    const int bx = k8 * 10 + (jj >> 3);   // bx=79 is padding (stores skipped)
    const int by = jj & 7;
    const int mBase = bx * 128;
    const int nBase = by * 64;

    const int t = threadIdx.x;
    const int wid = t >> 6, lane = t & 63;
    const int wr = (wid >> 1) * 64;
    const int wc = (wid & 1) * 32;
    const int fr = lane & 15;
    const int swz = (((lane >> 4) ^ (fr & 3)) << 3);

    const int srow   = lane >> 2;
    const int schunk = ((lane & 3) ^ (srow & 3)) * 8;
    const int arow0  = min(mBase + wid * 16 + srow, N_NODES - 1);
    const int arow1  = min(mBase + (wid + 4) * 16 + srow, N_NODES - 1);
    const int brow   = nBase + wid * 16 + srow;

    f32x4 acc[4][2] = {};

#define STAGE1(c, k0)                                                              \
    do {                                                                           \
        GLOAD_LDS16(&xb[(size_t)arow0 * KP + (k0) + schunk], &As[c][wid * 512]);   \
        GLOAD_LDS16(&xb[(size_t)arow1 * KP + (k0) + schunk], &As[c][(wid + 4) * 512]); \
        GLOAD_LDS16(&w1t[(size_t)brow * KP + (k0) + schunk], &Bs[c][wid * 512]);   \
    } while (0)

#define COMPUTE1(c)                                                            \
    do {                                                                       \
        bf16x8 af[4], bfv[2];                                                  \
        _Pragma("unroll")                                                      \
        for (int m = 0; m < 4; ++m)                                            \
            af[m] = *(const bf16x8*)&As[c][(wr + m * 16 + fr) * 32 + swz];     \
        _Pragma("unroll")                                                      \
        for (int n = 0; n < 2; ++n)                                            \
            bfv[n] = *(const bf16x8*)&Bs[c][(wc + n * 16 + fr) * 32 + swz];    \
        _Pragma("unroll")                                                      \
        for (int m = 0; m < 4; ++m)                                            \
            _Pragma("unroll")                                                  \
            for (int n = 0; n < 2; ++n)                                        \
                acc[m][n] = __builtin_amdgcn_mfma_f32_16x16x32_bf16(af[m], bfv[n], acc[m][n], 0, 0, 0); \
    } while (0)

    STAGE1(0, 0);
    int cur = 0;
    for (int tt = 0; tt < NT - 1; ++tt) {
        STAGE1(cur ^ 1, (tt + 1) * 32);
        asm volatile("s_waitcnt vmcnt(3)" ::: "memory");
        __builtin_amdgcn_s_barrier();
        __builtin_amdgcn_sched_barrier(0);
        COMPUTE1(cur);
        asm volatile("s_waitcnt lgkmcnt(0)" ::: "memory");
        __builtin_amdgcn_sched_barrier(0);
        __builtin_amdgcn_s_barrier();
        cur ^= 1;
    }
    asm volatile("s_waitcnt vmcnt(0)" ::: "memory");
    __builtin_amdgcn_s_barrier();
    COMPUTE1(cur);

#undef STAGE1
#undef COMPUTE1

    #pragma unroll
    for (int m = 0; m < 4; ++m) {
        int rbase = mBase + wr + m * 16 + (lane >> 4) * 4;
        #pragma unroll
        for (int n = 0; n < 2; ++n) {
            int col = nBase + wc + n * 16 + (lane & 15);
            #pragma unroll
            for (int i = 0; i < 4; ++i) {
                int row = rbase + i;
                if (row < N_NODES)
                    Cb[(size_t)row * H1 + col] = f2b(acc[m][n][i]);
            }
        }
    }
}

// ---------------------------------------------------------------------------
// FUSED gather h1 (+ReLU) + GEMM2/3. R11: 2-way edge unroll with dual
// accumulators -> 2 independent 16B/lane gathers in flight per wave
// (gather was latency-bound: 1 dependent load/iter at runtime-deg loop).
// ---------------------------------------------------------------------------
__global__ __launch_bounds__(512) void gather_gemm23(const unsigned short* __restrict__ sup,
                                                     const int* __restrict__ cnt,
                                                     const int* __restrict__ bsrc,
                                                     const float* __restrict__ bw,
                                                     const float* __restrict__ W2,
                                                     const float* __restrict__ W3,
                                                     unsigned short* __restrict__ sup2b) {
    __shared__ float hs[16][H1];   // 32 KB
    const int t = threadIdx.x;
    const int wid = t >> 6, lane = t & 63;
    const int rBase = blockIdx.x * 16;

    #pragma unroll
    for (int i = 0; i < 2; ++i) {
        const int local = wid * 2 + i;
        const int n = rBase + local;
        const int deg = min(cnt[n], CAP);
        float acc0[8] = {}, acc1[8] = {};
        int e = 0;
        for (; e + 2 <= deg; e += 2) {
            int   s0 = bsrc[n * CAP + e];
            int   s1 = bsrc[n * CAP + e + 1];
            float w0 = bw[n * CAP + e];
            float w1 = bw[n * CAP + e + 1];
            us8 v0 = *(const us8*)&sup[(size_t)s0 * H1 + lane * 8];
            us8 v1 = *(const us8*)&sup[(size_t)s1 * H1 + lane * 8];
            #pragma unroll
            for (int j = 0; j < 8; ++j) {
                acc0[j] += w0 * b2f(v0[j]);
                acc1[j] += w1 * b2f(v1[j]);
            }
        }
        if (e < deg) {
            int   s0 = bsrc[n * CAP + e];
            float w0 = bw[n * CAP + e];
            us8 v0 = *(const us8*)&sup[(size_t)s0 * H1 + lane * 8];
            #pragma unroll
            for (int j = 0; j < 8; ++j) acc0[j] += w0 * b2f(v0[j]);
        }
        #pragma unroll
        for (int j = 0; j < 8; ++j) acc0[j] += acc1[j];
        *(float4*)&hs[local][lane * 8] =
            make_float4(fmaxf(acc0[0], 0.f), fmaxf(acc0[1], 0.f), fmaxf(acc0[2], 0.f), fmaxf(acc0[3], 0.f));
        *(float4*)&hs[local][lane * 8 + 4] =
            make_float4(fmaxf(acc0[4], 0.f), fmaxf(acc0[5], 0.f), fmaxf(acc0[6], 0.f), fmaxf(acc0[7], 0.f));
    }
    __syncthreads();

    const int col = t & 127;
    const int rg  = (t >> 7) * 4;
    const float* W = (col < 64) ? (W2 + col) : (W3 + (col - 64));
    float acc2[4] = {};
    for (int k = 0; k < H1; ++k) {
        float wv = W[k * 64];
        #pragma unroll
        for (int i = 0; i < 4; ++i) acc2[i] += wv * hs[rg + i][k];
    }
    #pragma unroll
    for (int i = 0; i < 4; ++i)
        sup2b[(size_t)(rBase + rg + i) * 128 + col] = f2b(acc2[i]);
}

// ---------------------------------------------------------------------------
// Gather mu/logvar from bf16 sup2: 16 nodes/block, 16 lanes x us8 per node.
// 2-way edge unroll for MLP (same rationale as gather_gemm23).
// ---------------------------------------------------------------------------
__global__ __launch_bounds__(256) void gather_muvar(const unsigned short* __restrict__ sup2b,
                                                    const int* __restrict__ cnt,
                                                    const int* __restrict__ bsrc,
                                                    const float* __restrict__ bw,
                                                    float* __restrict__ mu,
                                                    float* __restrict__ lv,
                                                    unsigned short* __restrict__ mub) {
    const int n  = blockIdx.x * 16 + (threadIdx.x >> 4);
    const int c8 = (threadIdx.x & 15) * 8;
    const int deg = min(cnt[n], CAP);
    float acc0[8] = {}, acc1[8] = {};
    int e = 0;
    for (; e + 2 <= deg; e += 2) {
        int   s0 = bsrc[n * CAP + e];
        int   s1 = bsrc[n * CAP + e + 1];
        float w0 = bw[n * CAP + e];
        float w1 = bw[n * CAP + e + 1];
        us8 v0 = *(const us8*)&sup2b[(size_t)s0 * 128 + c8];
        us8 v1 = *(const us8*)&sup2b[(size_t)s1 * 128 + c8];
        #pragma unroll
        for (int j = 0; j < 8; ++j) {
            acc0[j] += w0 * b2f(v0[j]);
            acc1[j] += w1 * b2f(v1[j]);
        }
    }
    if (e < deg) {
        int   s0 = bsrc[n * CAP + e];
        float w0 = bw[n * CAP + e];
        us8 v0 = *(const us8*)&sup2b[(size_t)s0 * 128 + c8];
        #pragma unroll
        for (int j = 0; j < 8; ++j) acc0[j] += w0 * b2f(v0[j]);
    }
    #pragma unroll
    for (int j = 0; j < 8; ++j) acc0[j] += acc1[j];

    if (c8 < 64) {
        *(float4*)&mu[(size_t)n * 64 + c8]     = make_float4(acc0[0], acc0[1], acc0[2], acc0[3]);
        *(float4*)&mu[(size_t)n * 64 + c8 + 4] = make_float4(acc0[4], acc0[5], acc0[6], acc0[7]);
        us8 o;
        #pragma unroll
        for (int j = 0; j < 8; ++j) o[j] = f2b(acc0[j]);
        *(us8*)&mub[(size_t)n * 64 + c8] = o;
    } else {
        *(float4*)&lv[(size_t)n * 64 + (c8 - 64)]     = make_float4(acc0[0], acc0[1], acc0[2], acc0[3]);
        *(float4*)&lv[(size_t)n * 64 + (c8 - 64) + 4] = make_float4(acc0[4], acc0[5], acc0[6], acc0[7]);
    }
}

// ---------------------------------------------------------------------------
// pred = mu @ mu.T via bf16 MFMA; mub (1.28 MB) is L2-resident.
// LDS-staged coalesced rows + nontemporal stores (400 MB write-once stream).
// ---------------------------------------------------------------------------
__global__ __launch_bounds__(256) void pred_mfma(const unsigned short* __restrict__ mub,
                                                 float* __restrict__ pred) {
    __shared__ float st[4][16][68];
    const int t = threadIdx.x, wid = t >> 6, lane = t & 63;
    const int rb = blockIdx.x * 128 + (wid >> 1) * 64;
    const int cb = blockIdx.y * 128 + (wid & 1) * 64;
    const int fr = lane & 15, fk = (lane >> 4) * 8;
    f32x4 acc[4][4] = {};

    #pragma unroll
    for (int ks = 0; ks < 2; ++ks) {
        bf16x8 af[4], bfv[4];
        #pragma unroll
        for (int m = 0; m < 4; ++m) {
            int r = min(rb + m * 16 + fr, N_NODES - 1);
            af[m] = *(const bf16x8*)&mub[(size_t)r * 64 + ks * 32 + fk];
        }
        #pragma unroll
        for (int n = 0; n < 4; ++n) {
            int c = min(cb + n * 16 + fr, N_NODES - 1);
            bfv[n] = *(const bf16x8*)&mub[(size_t)c * 64 + ks * 32 + fk];
        }
        #pragma unroll
        for (int m = 0; m < 4; ++m)
            #pragma unroll
            for (int n = 0; n < 4; ++n)
                acc[m][n] = __builtin_amdgcn_mfma_f32_16x16x32_bf16(af[m], bfv[n], acc[m][n], 0, 0, 0);
    }

    #pragma unroll
    for (int m = 0; m < 4; ++m) {
        #pragma unroll
        for (int n = 0; n < 4; ++n)
            #pragma unroll
            for (int i = 0; i < 4; ++i)
                st[wid][(lane >> 4) * 4 + i][n * 16 + (lane & 15)] = acc[m][n][i];
        // wave-private region: in-wave lgkmcnt ordering suffices (no barrier)
        int rbase = rb + m * 16;
        #pragma unroll
        for (int it = 0; it < 4; ++it) {
            int row   = it * 4 + (lane >> 4);
            int chunk = lane & 15;
            int grow  = rbase + row;
            int gcol  = cb + chunk * 4;
            if (grow < N_NODES) {
                f32x4 v = *(const f32x4*)&st[wid][row][chunk * 4];
                if (gcol + 3 < N_NODES) {
                    __builtin_nontemporal_store(v, (f32x4*)&pred[(size_t)grow * N_NODES + gcol]);
                } else {
                    #pragma unroll
                    for (int j = 0; j < 4; ++j)
                        if (gcol + j < N_NODES)
                            __builtin_nontemporal_store(v[j], &pred[(size_t)grow * N_NODES + gcol + j]);
                }
            }
        }
    }
}

// ---------------------------------------------------------------------------
extern "C" void kernel_launch(void* const* d_in, const int* in_sizes, int n_in,
                              void* d_out, int out_size, void* d_ws, size_t ws_size,
                              hipStream_t stream) {
    const float* x    = (const float*)d_in[0];
    const int*   esrc = (const int*)d_in[1];
    const int*   edst = (const int*)d_in[2];
    const float* ew   = (const float*)d_in[3];
    const float* W1   = (const float*)d_in[4];
    const float* W2   = (const float*)d_in[5];
    const float* W3   = (const float*)d_in[6];

    float* pred = (float*)d_out;
    float* mu   = pred + (size_t)N_NODES * N_NODES;
    float* lv   = mu   + (size_t)N_NODES * H2;

    char* ws = (char*)d_ws;
    unsigned short* sup1b = (unsigned short*)ws; ws += (size_t)N_NODES * H1 * sizeof(short);
    unsigned short* sup2b = (unsigned short*)ws; ws += (size_t)N_NODES * 2 * H2 * sizeof(short);
    int*   cnt      = (int*)ws;   ws += (size_t)N_NODES * sizeof(int);
    int*   bsrc     = (int*)ws;   ws += (size_t)N_NODES * CAP * sizeof(int);
    float* bw       = (float*)ws; ws += (size_t)N_NODES * CAP * sizeof(float);
    unsigned short* xb  = (unsigned short*)ws; ws += (size_t)N_NODES * KP * sizeof(short);
    unsigned short* w1t = (unsigned short*)ws; ws += (size_t)H1 * KP * sizeof(short);
    unsigned short* mub = (unsigned short*)ws; ws += (size_t)N_NODES * H2 * sizeof(short);

    (void)hipMemsetAsync(cnt, 0, N_NODES * sizeof(int), stream);
    prep<<<NB_BUCKET + NB_CONVX + NB_CONVW, 256, 0, stream>>>(esrc, edst, ew, x, W1,
                                                              cnt, bsrc, bw, xb, w1t);
    gemm1_mfma<<<640, 256, 0, stream>>>(xb, w1t, sup1b);
    gather_gemm23<<<N_NODES / 16, 512, 0, stream>>>(sup1b, cnt, bsrc, bw, W2, W3, sup2b);
    gather_muvar<<<N_NODES / 16, 256, 0, stream>>>(sup2b, cnt, bsrc, bw, mu, lv, mub);
    pred_mfma<<<dim3((N_NODES + 127) / 128, (N_NODES + 127) / 128), 256, 0, stream>>>(mub, pred);
}